// Round 6
// baseline (227.386 us; speedup 1.0000x reference)
//
#include <hip/hip_runtime.h>
#include <hip/hip_bf16.h>
#include <math.h>

// VQ-VAE VectorQuantizer: B=32,T=2048,D=64,K=1024 -> N=65536 rows.
// Round 6: single fused MFMA sweep (min1/min2 certificate) + exact scan for
// ambiguous rows. Proven pieces kept verbatim: MFMA fragment scheme (R5),
// exact R1 fmaf chain + numpy-pairwise sums (R1-R5, absmax 0.0).
//  - certificate: d' = fl(se_j - 2*acc_mfma) tracked per row; if second-min
//    > min + EPSB (EPSB=1.5e-4 >= ~7x worst-case 2*delta), min1's col IS the
//    exact argmin. Else row -> exact full scan (bitwise R1 semantics).
//  - B-fragments staged in LDS per block (4 waves share), double-buffered,
//    reg-staged a tile ahead: cuts L2 B-traffic 8x vs R5's two passes.

typedef __attribute__((ext_vector_type(8))) short bf16x8;
typedef __attribute__((ext_vector_type(4))) float f32x4;

namespace {
constexpr int NROWS  = 65536;
constexpr int DDIM   = 64;
constexpr int KCODES = 1024;
constexpr float EPSB = 1.5e-4f;  // d'-space band

// ws layout (bytes) — ~772 KB
constexpr size_t WS_LOSS = 0;                        // double
constexpr size_t WS_CNT  = 64;                       // int
constexpr size_t WS_SE   = 256;                      // float[1024]
constexpr size_t WS_EHB  = WS_SE  + 4096;            // bf16 frags, 128 KB
constexpr size_t WS_ELB  = WS_EHB + (size_t)65536 * 2;
constexpr size_t WS_BIDX = WS_ELB + (size_t)65536 * 2;   // int[N]
constexpr size_t WS_LIST = WS_BIDX + (size_t)NROWS * 4;  // int[N]
}

__device__ inline short f2bf(float v) {
  __hip_bfloat16 h = __float2bfloat16(v);
  return *reinterpret_cast<short*>(&h);
}
__device__ inline float bf2f(short s) {
  __hip_bfloat16 h;
  *reinterpret_cast<short*>(&h) = s;
  return __bfloat162float(h);
}
__device__ inline f32x4 mfma16(bf16x8 a, bf16x8 b, f32x4 c) {
  return __builtin_amdgcn_mfma_f32_16x16x32_bf16(a, b, c, 0, 0, 0);
}
__device__ inline unsigned int fflip(unsigned int b) {
  return b ^ ((unsigned int)((int)b >> 31) | 0x80000000u);
}

// ---------------- prep: se (numpy pairwise), eh/el fragment pack, zero accums
__global__ __launch_bounds__(256) void vq_prep(const float* __restrict__ emb,
                                               float* __restrict__ se,
                                               short* __restrict__ ehB,
                                               short* __restrict__ elB,
                                               double* __restrict__ loss_accum,
                                               int* __restrict__ cnt) {
  #pragma clang fp contract(off)
  const int gid = blockIdx.x * 256 + (int)threadIdx.x;  // grid = 8192
  if (gid == 0) { *loss_accum = 0.0; *cnt = 0; }

  if (gid < KCODES) {   // se[j]: proven pairwise pattern
    const float* e = emb + (size_t)gid * DDIM;
    float r[8];
    #pragma unroll
    for (int j = 0; j < 8; ++j) r[j] = e[j] * e[j];
    #pragma unroll
    for (int i = 8; i < DDIM; i += 8) {
      #pragma unroll
      for (int j = 0; j < 8; ++j) r[j] += e[i + j] * e[i + j];
    }
    se[gid] = ((r[0] + r[1]) + (r[2] + r[3])) + ((r[4] + r[5]) + (r[6] + r[7]));
  }

  // pack frag (t,dc): lane l holds e[t*16+(l&15)][dc*32+(l>>4)*8 + i]  (R5-proven)
  const int t  = gid >> 7;
  const int dc = (gid >> 6) & 1;
  const int l  = gid & 63;
  const int code = t * 16 + (l & 15);
  const int d0   = dc * 32 + (l >> 4) * 8;
  const float* ep = emb + (size_t)code * DDIM + d0;
  const size_t ob = ((size_t)(t * 2 + dc) * 64 + l) * 8;
  #pragma unroll
  for (int i = 0; i < 8; ++i) {
    const float v = ep[i];
    const short h = f2bf(v);
    ehB[ob + i] = h;
    elB[ob + i] = f2bf(v - bf2f(h));
  }
}

// ---------------- fused sweep: block = 128 rows (4 waves x 32), K=1024
__global__ __launch_bounds__(256, 1) void vq_fused(const float* __restrict__ x,
                                                   const short* __restrict__ ehB,
                                                   const short* __restrict__ elB,
                                                   const float* __restrict__ se,
                                                   int* __restrict__ bidx,
                                                   int* __restrict__ list,
                                                   int* __restrict__ cnt) {
  #pragma clang fp contract(off)
  __shared__ __align__(16) short lbuf[2][4][512];   // [buf][frag][lane*8]
  __shared__ float sel[KCODES];                     // se staged once

  const int tid = (int)threadIdx.x;
  const int l   = tid & 63;
  const int wid = tid >> 6;

  #pragma unroll
  for (int i = 0; i < 4; ++i) sel[i * 256 + tid] = se[i * 256 + tid];

  // A-fragments for 2 row-tiles (32 rows/wave)
  const int wrb = blockIdx.x * 128 + wid * 32;
  bf16x8 xh[2][2], xl[2][2];
  #pragma unroll
  for (int rt = 0; rt < 2; ++rt) {
    const float* xp = x + (size_t)(wrb + rt * 16 + (l & 15)) * DDIM + (l >> 4) * 8;
    #pragma unroll
    for (int dc = 0; dc < 2; ++dc) {
      const float4 v0 = *reinterpret_cast<const float4*>(xp + dc * 32);
      const float4 v1 = *reinterpret_cast<const float4*>(xp + dc * 32 + 4);
      const float vv[8] = {v0.x, v0.y, v0.z, v0.w, v1.x, v1.y, v1.z, v1.w};
      #pragma unroll
      for (int i = 0; i < 8; ++i) {
        const short h = f2bf(vv[i]);
        xh[rt][dc][i] = h;
        xl[rt][dc][i] = f2bf(vv[i] - bf2f(h));
      }
    }
  }

  float m1v[2][4], m2v[2][4];
  int   m1t[2][4];
  #pragma unroll
  for (int rt = 0; rt < 2; ++rt)
    #pragma unroll
    for (int r = 0; r < 4; ++r) { m1v[rt][r] = INFINITY; m2v[rt][r] = INFINITY; m1t[rt][r] = 0; }

  // stage tile 0: wave w loads frag w
  const short* gsrc = (wid < 2) ? ehB : elB;
  const int fsub = wid & 1;
  bf16x8 pv = *reinterpret_cast<const bf16x8*>(gsrc + ((size_t)(0 * 2 + fsub) * 64 + l) * 8);
  *reinterpret_cast<bf16x8*>(&lbuf[0][wid][l * 8]) = pv;
  __syncthreads();

  const f32x4 kz = {0.f, 0.f, 0.f, 0.f};
  for (int t = 0; t < 64; ++t) {
    const int p = t & 1;
    if (t < 63)   // prefetch next tile's frag to regs (in flight during compute)
      pv = *reinterpret_cast<const bf16x8*>(gsrc + ((size_t)((t + 1) * 2 + fsub) * 64 + l) * 8);

    const bf16x8 eh0 = *reinterpret_cast<const bf16x8*>(&lbuf[p][0][l * 8]);
    const bf16x8 eh1 = *reinterpret_cast<const bf16x8*>(&lbuf[p][1][l * 8]);
    const bf16x8 el0 = *reinterpret_cast<const bf16x8*>(&lbuf[p][2][l * 8]);
    const bf16x8 el1 = *reinterpret_cast<const bf16x8*>(&lbuf[p][3][l * 8]);

    f32x4 a0, a1;   // interleave the two row-tiles: dep distance 2 on MFMA pipe
    a0 = mfma16(xh[0][0], eh0, kz);  a1 = mfma16(xh[1][0], eh0, kz);
    a0 = mfma16(xh[0][1], eh1, a0);  a1 = mfma16(xh[1][1], eh1, a1);
    a0 = mfma16(xh[0][0], el0, a0);  a1 = mfma16(xh[1][0], el0, a1);
    a0 = mfma16(xh[0][1], el1, a0);  a1 = mfma16(xh[1][1], el1, a1);
    a0 = mfma16(xl[0][0], eh0, a0);  a1 = mfma16(xl[1][0], eh0, a1);
    a0 = mfma16(xl[0][1], eh1, a0);  a1 = mfma16(xl[1][1], eh1, a1);

    const float sev = sel[t * 16 + (l & 15)];   // broadcast-friendly LDS read
    #pragma unroll
    for (int r = 0; r < 4; ++r) {
      {
        const float d = __builtin_fmaf(-2.0f, a0[r], sev);  // d' = se - 2*dot
        const bool c = d < m1v[0][r];
        m2v[0][r] = fminf(m2v[0][r], fmaxf(m1v[0][r], d));
        m1t[0][r] = c ? t : m1t[0][r];
        m1v[0][r] = fminf(m1v[0][r], d);
      }
      {
        const float d = __builtin_fmaf(-2.0f, a1[r], sev);
        const bool c = d < m1v[1][r];
        m2v[1][r] = fminf(m2v[1][r], fmaxf(m1v[1][r], d));
        m1t[1][r] = c ? t : m1t[1][r];
        m1v[1][r] = fminf(m1v[1][r], d);
      }
    }

    __syncthreads();                      // all waves done reading lbuf[p]
    if (t < 63) {
      *reinterpret_cast<bf16x8*>(&lbuf[p ^ 1][wid][l * 8]) = pv;
      __syncthreads();                    // next tile staged
    }
  }

  // cross-lane merge within 16-lane groups; resolve or flag
  const int colbase = l & 15;
  #pragma unroll
  for (int rt = 0; rt < 2; ++rt) {
    #pragma unroll
    for (int r = 0; r < 4; ++r) {
      float m1 = m1v[rt][r], m2 = m2v[rt][r];
      unsigned long long key =
          ((unsigned long long)fflip(__float_as_uint(m1)) << 32)
          | (unsigned)(m1t[rt][r] * 16 + colbase);
      #pragma unroll
      for (int off = 1; off < 16; off <<= 1) {
        const unsigned long long ok = __shfl_xor(key, off, 16);
        const float om1 = __shfl_xor(m1, off, 16);
        const float om2 = __shfl_xor(m2, off, 16);
        m2 = fminf(fminf(m2, om2), fmaxf(m1, om1));
        m1 = fminf(m1, om1);
        key = (ok < key) ? ok : key;
      }
      if (colbase == 0) {
        const int row = wrb + rt * 16 + (l >> 4) * 4 + r;
        if (m2 > m1 + EPSB) {
          bidx[row] = (int)(key & 0xffffffffull);     // certified exact argmin
        } else {
          const int pos = atomicAdd(cnt, 1);
          list[pos] = row;                            // ambiguous -> exact scan
        }
      }
    }
  }
}

// ---------------- exact scan for flagged rows (bitwise R1 semantics)
__global__ __launch_bounds__(256) void vq_exact(const float* __restrict__ x,
                                                const float* __restrict__ emb,
                                                const float* __restrict__ se,
                                                const int* __restrict__ list,
                                                const int* __restrict__ cnt,
                                                int* __restrict__ bidx) {
  #pragma clang fp contract(off)
  const int nw = (int)gridDim.x * 4;
  const int gw = blockIdx.x * 4 + ((int)threadIdx.x >> 6);
  const int l  = (int)threadIdx.x & 63;
  const int n  = *cnt;

  for (int idx = gw; idx < n; idx += nw) {
    const int row = list[idx];
    const float* xr = x + (size_t)row * DDIM;

    // sx: numpy pairwise 8-accumulator (uniform loads; proven pattern)
    float rr[8];
    #pragma unroll
    for (int j = 0; j < 8; ++j) rr[j] = xr[j] * xr[j];
    #pragma unroll
    for (int i = 8; i < DDIM; i += 8) {
      #pragma unroll
      for (int j = 0; j < 8; ++j) rr[j] += xr[i + j] * xr[i + j];
    }
    const float sx = ((rr[0] + rr[1]) + (rr[2] + rr[3])) + ((rr[4] + rr[5]) + (rr[6] + rr[7]));

    unsigned long long best = ~0ull;
    for (int jj = 0; jj < 16; ++jj) {
      const int j = l * 16 + jj;
      const float* ep = emb + (size_t)j * DDIM;
      float acc = 0.0f;
      #pragma unroll
      for (int q = 0; q < 16; ++q) {   // sequential d=0..63 fmaf chain (R1)
        const float4 xv = reinterpret_cast<const float4*>(xr)[q];
        const float4 ev = reinterpret_cast<const float4*>(ep)[q];
        acc = __builtin_fmaf(xv.x, ev.x, acc);
        acc = __builtin_fmaf(xv.y, ev.y, acc);
        acc = __builtin_fmaf(xv.z, ev.z, acc);
        acc = __builtin_fmaf(xv.w, ev.w, acc);
      }
      const float T = sx + se[j];                        // fl(sx + se_j)
      const float dist = __builtin_fmaf(-2.0f, acc, T);  // fl(T - 2*acc)
      const unsigned long long key =
          ((unsigned long long)fflip(__float_as_uint(dist)) << 32) | (unsigned)j;
      best = (key < best) ? key : best;
    }
    #pragma unroll
    for (int off = 32; off > 0; off >>= 1) {
      const unsigned long long o = __shfl_xor(best, off, 64);
      best = (o < best) ? o : best;
    }
    if (l == 0) bidx[row] = (int)(best & 0xffffffffull);
  }
}

// ---------------- finalize: gather, straight-through out, index, loss
__global__ __launch_bounds__(256) void vq_finalize(const float* __restrict__ x,
                                                   const float* __restrict__ emb,
                                                   const int* __restrict__ bidx,
                                                   float* __restrict__ out,
                                                   double* __restrict__ loss_accum) {
  #pragma clang fp contract(off)
  const int row = blockIdx.x * 256 + (int)threadIdx.x;
  const int bi = bidx[row];

  const float* xr = x + (size_t)row * DDIM;
  const float* ep = emb + (size_t)bi * DDIM;
  float* orow = out + (size_t)row * DDIM;
  float lsum = 0.0f;
  #pragma unroll
  for (int d = 0; d < DDIM; ++d) {
    const float xd = xr[d];
    const float q  = ep[d];
    const float diff = q - xd;
    orow[d] = xd + diff;
    lsum += diff * diff;
  }
  out[(size_t)NROWS * DDIM + row] = (float)bi;

  #pragma unroll
  for (int off = 32; off > 0; off >>= 1) lsum += __shfl_down(lsum, off, 64);
  if ((threadIdx.x & 63) == 0) atomicAdd(loss_accum, (double)lsum);
}

// ---------------- scalars
__global__ void vq_scalars(const double* __restrict__ loss_accum,
                           float* __restrict__ out) {
  if (threadIdx.x == 0 && blockIdx.x == 0) {
    const double mm = *loss_accum / (double)((size_t)NROWS * DDIM);
    const float el = (float)mm;
    float* tail = out + (size_t)NROWS * DDIM + NROWS;
    tail[0] = 0.25f * el;
    tail[1] = el;
    tail[2] = 0.0f;
  }
}

// ============================================================================
extern "C" void kernel_launch(void* const* d_in, const int* in_sizes, int n_in,
                              void* d_out, int out_size, void* d_ws, size_t ws_size,
                              hipStream_t stream) {
  const float* x   = (const float*)d_in[0];  // [N, 64]
  const float* emb = (const float*)d_in[1];  // [K, 64]
  float* out = (float*)d_out;
  char* ws = (char*)d_ws;

  double* loss_accum = (double*)(ws + WS_LOSS);
  int*    cnt        = (int*)(ws + WS_CNT);
  float*  se         = (float*)(ws + WS_SE);
  short*  ehB        = (short*)(ws + WS_EHB);
  short*  elB        = (short*)(ws + WS_ELB);
  int*    bidx       = (int*)(ws + WS_BIDX);
  int*    list       = (int*)(ws + WS_LIST);

  vq_prep<<<32, 256, 0, stream>>>(emb, se, ehB, elB, loss_accum, cnt);
  vq_fused<<<NROWS / 128, 256, 0, stream>>>(x, ehB, elB, se, bidx, list, cnt);
  vq_exact<<<512, 256, 0, stream>>>(x, emb, se, list, cnt, bidx);
  vq_finalize<<<NROWS / 256, 256, 0, stream>>>(x, emb, bidx, out, loss_accum);
  vq_scalars<<<1, 64, 0, stream>>>(loss_accum, out);
}

// Round 7
// 164.297 us; speedup vs baseline: 1.3840x; 1.3840x over previous
//
#include <hip/hip_runtime.h>
#include <hip/hip_bf16.h>
#include <math.h>

// VQ-VAE VectorQuantizer: B=32,T=2048,D=64,K=1024 -> N=65536 rows.
// Round 7: barrier-free fused MFMA sweep (min1/min2 certificate, B direct
// from L2, reg-prefetch) + R1-structure exact scan for ambiguous rows.
// Proven pieces kept verbatim: MFMA fragment scheme (R5/R6), min1/min2/tile
// tracking + 16-lane merge (R6), exact R1 fmaf chain + numpy-pairwise sums
// (R1-R6, absmax 0.0 every round).
//  - certificate: d' = fl(se_j - 2*acc_mfma); if second-min > min + EPSB the
//    min1 col is the exact argmin (pairwise noise bound ~1.8e-5; EPSB=8e-5
//    gives 4.7x margin). Ambiguous rows (~2%) -> exact scan, bitwise R1.
//  - exact scan: lane = gathered row, codes wave-uniform (s_load broadcast),
//    32-way code partition; u64 key fflip(dist)<<32|j atomicMin => global
//    first-min across partitions.

typedef __attribute__((ext_vector_type(8))) short bf16x8;
typedef __attribute__((ext_vector_type(4))) float f32x4;

namespace {
constexpr int NROWS  = 65536;
constexpr int DDIM   = 64;
constexpr int KCODES = 1024;
constexpr float EPSB = 8e-5f;   // certificate band; bound ~1.8e-5, 4.7x margin

// ws layout (bytes) — ~1.26 MB
constexpr size_t WS_LOSS = 0;                            // double
constexpr size_t WS_CNT  = 64;                           // int
constexpr size_t WS_SE   = 256;                          // float[1024]
constexpr size_t WS_EHB  = 8192;                         // bf16 frags 128 KB
constexpr size_t WS_ELB  = WS_EHB + (size_t)65536 * 2;   // 128 KB
constexpr size_t WS_BIDX = WS_ELB + (size_t)65536 * 2;   // int[N]
constexpr size_t WS_LIST = WS_BIDX + (size_t)NROWS * 4;  // int[N]
constexpr size_t WS_KEY  = WS_LIST + (size_t)NROWS * 4;  // u64[N]
}

__device__ inline short f2bf(float v) {
  __hip_bfloat16 h = __float2bfloat16(v);
  return *reinterpret_cast<short*>(&h);
}
__device__ inline float bf2f(short s) {
  __hip_bfloat16 h;
  *reinterpret_cast<short*>(&h) = s;
  return __bfloat162float(h);
}
__device__ inline f32x4 mfma16(bf16x8 a, bf16x8 b, f32x4 c) {
  return __builtin_amdgcn_mfma_f32_16x16x32_bf16(a, b, c, 0, 0, 0);
}
__device__ inline unsigned int fflip(unsigned int b) {
  return b ^ ((unsigned int)((int)b >> 31) | 0x80000000u);
}

// ---------------- prep: init keyBest/loss/cnt, se (numpy pairwise), frag pack
__global__ __launch_bounds__(256) void vq_prep(const float* __restrict__ emb,
                                               float* __restrict__ se,
                                               short* __restrict__ ehB,
                                               short* __restrict__ elB,
                                               unsigned long long* __restrict__ keyBest,
                                               double* __restrict__ loss_accum,
                                               int* __restrict__ cnt) {
  #pragma clang fp contract(off)
  const int gid = blockIdx.x * 256 + (int)threadIdx.x;   // grid = 65536
  if (gid == 0) { *loss_accum = 0.0; *cnt = 0; }
  keyBest[gid] = ~0ull;

  if (gid < KCODES) {   // se[j]: proven pairwise pattern
    const float* e = emb + (size_t)gid * DDIM;
    float r[8];
    #pragma unroll
    for (int j = 0; j < 8; ++j) r[j] = e[j] * e[j];
    #pragma unroll
    for (int i = 8; i < DDIM; i += 8) {
      #pragma unroll
      for (int j = 0; j < 8; ++j) r[j] += e[i + j] * e[i + j];
    }
    se[gid] = ((r[0] + r[1]) + (r[2] + r[3])) + ((r[4] + r[5]) + (r[6] + r[7]));
  }

  // pack frag (t,dc): lane l holds e[t*16+(l&15)][dc*32+(l>>4)*8 + i]  (R5/R6)
  if (gid < 8192) {
    const int t  = gid >> 7;
    const int dc = (gid >> 6) & 1;
    const int l  = gid & 63;
    const int code = t * 16 + (l & 15);
    const int d0   = dc * 32 + (l >> 4) * 8;
    const float* ep = emb + (size_t)code * DDIM + d0;
    const size_t ob = ((size_t)(t * 2 + dc) * 64 + l) * 8;
    #pragma unroll
    for (int i = 0; i < 8; ++i) {
      const float v = ep[i];
      const short h = f2bf(v);
      ehB[ob + i] = h;
      elB[ob + i] = f2bf(v - bf2f(h));
    }
  }
}

// ---------------- fused sweep: wave = 32 rows x 1024 codes, no barriers
__global__ __launch_bounds__(256, 4) void vq_fused(const float* __restrict__ x,
                                                   const short* __restrict__ ehB,
                                                   const short* __restrict__ elB,
                                                   const float* __restrict__ se,
                                                   int* __restrict__ bidx,
                                                   int* __restrict__ list,
                                                   int* __restrict__ cnt) {
  #pragma clang fp contract(off)
  __shared__ float sel[KCODES];
  const int tid = (int)threadIdx.x;
  const int l   = tid & 63;
  const int wid = tid >> 6;
  #pragma unroll
  for (int i = 0; i < 4; ++i) sel[i * 256 + tid] = se[i * 256 + tid];
  __syncthreads();

  // A-fragments for 2 row-tiles (32 rows/wave)
  const int wrb = blockIdx.x * 128 + wid * 32;
  bf16x8 xh[2][2], xl[2][2];
  #pragma unroll
  for (int rt = 0; rt < 2; ++rt) {
    const float* xp = x + (size_t)(wrb + rt * 16 + (l & 15)) * DDIM + (l >> 4) * 8;
    #pragma unroll
    for (int dc = 0; dc < 2; ++dc) {
      const float4 v0 = *reinterpret_cast<const float4*>(xp + dc * 32);
      const float4 v1 = *reinterpret_cast<const float4*>(xp + dc * 32 + 4);
      const float vv[8] = {v0.x, v0.y, v0.z, v0.w, v1.x, v1.y, v1.z, v1.w};
      #pragma unroll
      for (int i = 0; i < 8; ++i) {
        const short h = f2bf(vv[i]);
        xh[rt][dc][i] = h;
        xl[rt][dc][i] = f2bf(vv[i] - bf2f(h));
      }
    }
  }

  float m1v[2][4], m2v[2][4];
  int   m1t[2][4];
  #pragma unroll
  for (int rt = 0; rt < 2; ++rt)
    #pragma unroll
    for (int r = 0; r < 4; ++r) { m1v[rt][r] = INFINITY; m2v[rt][r] = INFINITY; m1t[rt][r] = 0; }

  const size_t lb = (size_t)l * 8;
  // prefetch tile 0 fragments to regs
  bf16x8 ch0 = *reinterpret_cast<const bf16x8*>(ehB + (size_t)(0 * 128) + lb);
  bf16x8 ch1 = *reinterpret_cast<const bf16x8*>(ehB + (size_t)(1 * 512) + lb);
  bf16x8 cl0 = *reinterpret_cast<const bf16x8*>(elB + (size_t)(0 * 128) + lb);
  bf16x8 cl1 = *reinterpret_cast<const bf16x8*>(elB + (size_t)(1 * 512) + lb);

  const f32x4 kz = {0.f, 0.f, 0.f, 0.f};
  for (int t = 0; t < 64; ++t) {
    bf16x8 nh0, nh1, nl0, nl1;
    if (t < 63) {   // issue next tile's loads now; consumed next iteration
      const size_t tb = (size_t)(t + 1) * 1024;
      nh0 = *reinterpret_cast<const bf16x8*>(ehB + tb + lb);
      nh1 = *reinterpret_cast<const bf16x8*>(ehB + tb + 512 + lb);
      nl0 = *reinterpret_cast<const bf16x8*>(elB + tb + lb);
      nl1 = *reinterpret_cast<const bf16x8*>(elB + tb + 512 + lb);
    }

    f32x4 a0, a1;   // interleave the two row-tiles: dep distance 2 on MFMA pipe
    a0 = mfma16(xh[0][0], ch0, kz);  a1 = mfma16(xh[1][0], ch0, kz);
    a0 = mfma16(xh[0][1], ch1, a0);  a1 = mfma16(xh[1][1], ch1, a1);
    a0 = mfma16(xh[0][0], cl0, a0);  a1 = mfma16(xh[1][0], cl0, a1);
    a0 = mfma16(xh[0][1], cl1, a0);  a1 = mfma16(xh[1][1], cl1, a1);
    a0 = mfma16(xl[0][0], ch0, a0);  a1 = mfma16(xl[1][0], ch0, a1);
    a0 = mfma16(xl[0][1], ch1, a0);  a1 = mfma16(xl[1][1], ch1, a1);

    const float sev = sel[t * 16 + (l & 15)];
    #pragma unroll
    for (int r = 0; r < 4; ++r) {
      {
        const float d = __builtin_fmaf(-2.0f, a0[r], sev);  // d' = se - 2*dot
        const bool c = d < m1v[0][r];
        m2v[0][r] = fminf(m2v[0][r], fmaxf(m1v[0][r], d));
        m1t[0][r] = c ? t : m1t[0][r];
        m1v[0][r] = fminf(m1v[0][r], d);
      }
      {
        const float d = __builtin_fmaf(-2.0f, a1[r], sev);
        const bool c = d < m1v[1][r];
        m2v[1][r] = fminf(m2v[1][r], fmaxf(m1v[1][r], d));
        m1t[1][r] = c ? t : m1t[1][r];
        m1v[1][r] = fminf(m1v[1][r], d);
      }
    }
    ch0 = nh0; ch1 = nh1; cl0 = nl0; cl1 = nl1;
  }

  // 16-lane merge (R6-proven); certificate or flag
  const int colbase = l & 15;
  #pragma unroll
  for (int rt = 0; rt < 2; ++rt) {
    #pragma unroll
    for (int r = 0; r < 4; ++r) {
      float m1 = m1v[rt][r], m2 = m2v[rt][r];
      unsigned long long key =
          ((unsigned long long)fflip(__float_as_uint(m1)) << 32)
          | (unsigned)(m1t[rt][r] * 16 + colbase);
      #pragma unroll
      for (int off = 1; off < 16; off <<= 1) {
        const unsigned long long ok = __shfl_xor(key, off, 16);
        const float om1 = __shfl_xor(m1, off, 16);
        const float om2 = __shfl_xor(m2, off, 16);
        m2 = fminf(fminf(m2, om2), fmaxf(m1, om1));
        m1 = fminf(m1, om1);
        key = (ok < key) ? ok : key;
      }
      if (colbase == 0) {
        const int row = wrb + rt * 16 + (l >> 4) * 4 + r;
        if (m2 > m1 + EPSB) {
          bidx[row] = (int)(key & 0xffffffffull);     // certified exact argmin
        } else {
          bidx[row] = -1;                              // ambiguous sentinel
          const int pos = atomicAdd(cnt, 1);
          list[pos] = row;
        }
      }
    }
  }
}

// ---------------- exact scan: lane = gathered row, 32-way code partition
__global__ __launch_bounds__(256) void vq_exact(const float* __restrict__ x,
                                                const float* __restrict__ emb,
                                                const float* __restrict__ se,
                                                const int* __restrict__ list,
                                                const int* __restrict__ cnt,
                                                unsigned long long* __restrict__ keyBest) {
  #pragma clang fp contract(off)
  const int n = *cnt;
  const int w = blockIdx.x * 4 + ((int)threadIdx.x >> 6);  // 1024 waves
  const int l = (int)threadIdx.x & 63;
  const int part = w & 31;                                 // 32 code-partitions

  for (int rb = (w >> 5); rb * 64 < n; rb += 32) {
    const int idx = rb * 64 + l;
    const bool act = idx < n;
    const int row = act ? list[idx] : list[0];
    const float* xr = x + (size_t)row * DDIM;

    float xv[DDIM];
    #pragma unroll
    for (int d = 0; d < DDIM; d += 4) {
      const float4 v = *reinterpret_cast<const float4*>(xr + d);
      xv[d] = v.x; xv[d + 1] = v.y; xv[d + 2] = v.z; xv[d + 3] = v.w;
    }
    // sx: numpy pairwise 8-accumulator (R1-proven)
    float rr[8];
    #pragma unroll
    for (int j = 0; j < 8; ++j) rr[j] = xv[j] * xv[j];
    #pragma unroll
    for (int i = 8; i < DDIM; i += 8) {
      #pragma unroll
      for (int j = 0; j < 8; ++j) rr[j] += xv[i + j] * xv[i + j];
    }
    const float sx = ((rr[0] + rr[1]) + (rr[2] + rr[3])) + ((rr[4] + rr[5]) + (rr[6] + rr[7]));

    unsigned long long best = ~0ull;
    for (int jj = 0; jj < 32; ++jj) {
      const int j = part * 32 + jj;                 // wave-uniform -> s_load
      const float* ep = emb + (size_t)j * DDIM;
      float acc = 0.0f;
      #pragma unroll
      for (int d = 0; d < DDIM; ++d) acc = __builtin_fmaf(xv[d], ep[d], acc);
      const float T = sx + se[j];                        // fl(sx + se_j)
      const float dist = __builtin_fmaf(-2.0f, acc, T);  // fl(T - 2*acc)
      const unsigned long long key =
          ((unsigned long long)fflip(__float_as_uint(dist)) << 32) | (unsigned)j;
      best = (key < best) ? key : best;
    }
    if (act) atomicMin(&keyBest[row], best);   // global first-min across parts
  }
}

// ---------------- finalize: gather, straight-through out, index, loss
__global__ __launch_bounds__(256) void vq_finalize(const float* __restrict__ x,
                                                   const float* __restrict__ emb,
                                                   const int* __restrict__ bidx,
                                                   const unsigned long long* __restrict__ keyBest,
                                                   float* __restrict__ out,
                                                   double* __restrict__ loss_accum) {
  #pragma clang fp contract(off)
  const int row = blockIdx.x * 256 + (int)threadIdx.x;
  int bi = bidx[row];
  if (bi < 0) bi = (int)(keyBest[row] & 0xffffffffull);

  const float* xr = x + (size_t)row * DDIM;
  const float* ep = emb + (size_t)bi * DDIM;
  float* orow = out + (size_t)row * DDIM;
  float lsum = 0.0f;
  #pragma unroll
  for (int d = 0; d < DDIM; ++d) {
    const float xd = xr[d];
    const float q  = ep[d];
    const float diff = q - xd;
    orow[d] = xd + diff;
    lsum += diff * diff;
  }
  out[(size_t)NROWS * DDIM + row] = (float)bi;

  #pragma unroll
  for (int off = 32; off > 0; off >>= 1) lsum += __shfl_down(lsum, off, 64);
  if ((threadIdx.x & 63) == 0) atomicAdd(loss_accum, (double)lsum);
}

// ---------------- scalars
__global__ void vq_scalars(const double* __restrict__ loss_accum,
                           float* __restrict__ out) {
  if (threadIdx.x == 0 && blockIdx.x == 0) {
    const double mm = *loss_accum / (double)((size_t)NROWS * DDIM);
    const float el = (float)mm;
    float* tail = out + (size_t)NROWS * DDIM + NROWS;
    tail[0] = 0.25f * el;
    tail[1] = el;
    tail[2] = 0.0f;
  }
}

// ============================================================================
extern "C" void kernel_launch(void* const* d_in, const int* in_sizes, int n_in,
                              void* d_out, int out_size, void* d_ws, size_t ws_size,
                              hipStream_t stream) {
  const float* x   = (const float*)d_in[0];  // [N, 64]
  const float* emb = (const float*)d_in[1];  // [K, 64]
  float* out = (float*)d_out;
  char* ws = (char*)d_ws;

  double* loss_accum = (double*)(ws + WS_LOSS);
  int*    cnt        = (int*)(ws + WS_CNT);
  float*  se         = (float*)(ws + WS_SE);
  short*  ehB        = (short*)(ws + WS_EHB);
  short*  elB        = (short*)(ws + WS_ELB);
  int*    bidx       = (int*)(ws + WS_BIDX);
  int*    list       = (int*)(ws + WS_LIST);
  unsigned long long* keyBest = (unsigned long long*)(ws + WS_KEY);

  vq_prep<<<NROWS / 256, 256, 0, stream>>>(emb, se, ehB, elB, keyBest,
                                           loss_accum, cnt);
  vq_fused<<<NROWS / 128, 256, 0, stream>>>(x, ehB, elB, se, bidx, list, cnt);
  vq_exact<<<256, 256, 0, stream>>>(x, emb, se, list, cnt, keyBest);
  vq_finalize<<<NROWS / 256, 256, 0, stream>>>(x, emb, bidx, keyBest, out,
                                               loss_accum);
  vq_scalars<<<1, 64, 0, stream>>>(loss_accum, out);
}

// Round 8
// 151.039 us; speedup vs baseline: 1.5055x; 1.0878x over previous
//
#include <hip/hip_runtime.h>
#include <hip/hip_bf16.h>
#include <math.h>

// VQ-VAE VectorQuantizer: B=32,T=2048,D=64,K=1024 -> N=65536 rows.
// Round 8: R7 structure with the three measured bottlenecks fixed:
//  - fused: 2-deep B prefetch (counted vmcnt, no loop-end drain), atomics
//    removed (sentinel only), unroll-4.
//  - new compact kernel: ballot-compaction of ambiguous rows (<=1024 atomics
//    vs R7's ~9k same-address atomicAdds in fused).
//  - exact: 4096 waves, 4 independent code-chains per lane (breaks the serial
//    256-cyc chain; each chain still the bit-exact sequential d=0..63 order),
//    chunk-streamed x (R3-proven low-VGPR shape).
//  - finalize: 16-lane x float4 per row -> coalesced e-gather.
// Frozen proven semantics: MFMA fragment scheme (R5-R7), min1/min2 certificate
// + 16-lane merge (R6/R7), exact R1 fmaf chain + numpy-pairwise sums
// (absmax 0.0 in all 7 rounds), EPSB=8e-5 (3.5x margin over 2.3e-5 bound).

typedef __attribute__((ext_vector_type(8))) short bf16x8;
typedef __attribute__((ext_vector_type(4))) float f32x4;

namespace {
constexpr int NROWS  = 65536;
constexpr int DDIM   = 64;
constexpr int KCODES = 1024;
constexpr float EPSB = 8e-5f;   // certificate band; bound ~2.3e-5

// ws layout (bytes) — ~1.8 MB
constexpr size_t WS_LOSS = 0;                            // double
constexpr size_t WS_CNT  = 64;                           // int
constexpr size_t WS_SE   = 256;                          // float[1024]
constexpr size_t WS_EHB  = 8192;                         // bf16 frags 128 KB
constexpr size_t WS_ELB  = WS_EHB + (size_t)65536 * 2;   // 128 KB
constexpr size_t WS_BIDX = WS_ELB + (size_t)65536 * 2;   // int[N]
constexpr size_t WS_LIST = WS_BIDX + (size_t)NROWS * 4;  // int[N]
constexpr size_t WS_KEY  = WS_LIST + (size_t)NROWS * 4;  // u64[N]
}

__device__ inline short f2bf(float v) {
  __hip_bfloat16 h = __float2bfloat16(v);
  return *reinterpret_cast<short*>(&h);
}
__device__ inline float bf2f(short s) {
  __hip_bfloat16 h;
  *reinterpret_cast<short*>(&h) = s;
  return __bfloat162float(h);
}
__device__ inline f32x4 mfma16(bf16x8 a, bf16x8 b, f32x4 c) {
  return __builtin_amdgcn_mfma_f32_16x16x32_bf16(a, b, c, 0, 0, 0);
}
__device__ inline unsigned int fflip(unsigned int b) {
  return b ^ ((unsigned int)((int)b >> 31) | 0x80000000u);
}

// ---------------- prep: init keyBest/loss/cnt, se (numpy pairwise), frag pack
__global__ __launch_bounds__(256) void vq_prep(const float* __restrict__ emb,
                                               float* __restrict__ se,
                                               short* __restrict__ ehB,
                                               short* __restrict__ elB,
                                               unsigned long long* __restrict__ keyBest,
                                               double* __restrict__ loss_accum,
                                               int* __restrict__ cnt) {
  #pragma clang fp contract(off)
  const int gid = blockIdx.x * 256 + (int)threadIdx.x;   // grid = 65536
  if (gid == 0) { *loss_accum = 0.0; *cnt = 0; }
  keyBest[gid] = ~0ull;

  if (gid < KCODES) {   // se[j]: proven pairwise pattern
    const float* e = emb + (size_t)gid * DDIM;
    float r[8];
    #pragma unroll
    for (int j = 0; j < 8; ++j) r[j] = e[j] * e[j];
    #pragma unroll
    for (int i = 8; i < DDIM; i += 8) {
      #pragma unroll
      for (int j = 0; j < 8; ++j) r[j] += e[i + j] * e[i + j];
    }
    se[gid] = ((r[0] + r[1]) + (r[2] + r[3])) + ((r[4] + r[5]) + (r[6] + r[7]));
  }

  // pack frag (t,dc): lane l holds e[t*16+(l&15)][dc*32+(l>>4)*8 + i]  (R5-R7)
  if (gid < 8192) {
    const int t  = gid >> 7;
    const int dc = (gid >> 6) & 1;
    const int l  = gid & 63;
    const int code = t * 16 + (l & 15);
    const int d0   = dc * 32 + (l >> 4) * 8;
    const float* ep = emb + (size_t)code * DDIM + d0;
    const size_t ob = ((size_t)(t * 2 + dc) * 64 + l) * 8;
    #pragma unroll
    for (int i = 0; i < 8; ++i) {
      const float v = ep[i];
      const short h = f2bf(v);
      ehB[ob + i] = h;
      elB[ob + i] = f2bf(v - bf2f(h));
    }
  }
}

// ---------------- fused sweep: wave = 32 rows x 1024 codes, 2-deep prefetch
__global__ __launch_bounds__(256, 2) void vq_fused(const float* __restrict__ x,
                                                   const short* __restrict__ ehB,
                                                   const short* __restrict__ elB,
                                                   const float* __restrict__ se,
                                                   int* __restrict__ bidx) {
  #pragma clang fp contract(off)
  __shared__ float sel[KCODES];
  const int tid = (int)threadIdx.x;
  const int l   = tid & 63;
  const int wid = tid >> 6;
  #pragma unroll
  for (int i = 0; i < 4; ++i) sel[i * 256 + tid] = se[i * 256 + tid];
  __syncthreads();

  // A-fragments for 2 row-tiles (32 rows/wave)
  const int wrb = blockIdx.x * 128 + wid * 32;
  bf16x8 xh[2][2], xl[2][2];
  #pragma unroll
  for (int rt = 0; rt < 2; ++rt) {
    const float* xp = x + (size_t)(wrb + rt * 16 + (l & 15)) * DDIM + (l >> 4) * 8;
    #pragma unroll
    for (int dc = 0; dc < 2; ++dc) {
      const float4 v0 = *reinterpret_cast<const float4*>(xp + dc * 32);
      const float4 v1 = *reinterpret_cast<const float4*>(xp + dc * 32 + 4);
      const float vv[8] = {v0.x, v0.y, v0.z, v0.w, v1.x, v1.y, v1.z, v1.w};
      #pragma unroll
      for (int i = 0; i < 8; ++i) {
        const short h = f2bf(vv[i]);
        xh[rt][dc][i] = h;
        xl[rt][dc][i] = f2bf(vv[i] - bf2f(h));
      }
    }
  }

  float m1v[2][4], m2v[2][4];
  int   m1t[2][4];
  #pragma unroll
  for (int rt = 0; rt < 2; ++rt)
    #pragma unroll
    for (int r = 0; r < 4; ++r) { m1v[rt][r] = INFINITY; m2v[rt][r] = INFINITY; m1t[rt][r] = 0; }

  const size_t lb = (size_t)l * 8;
#define FRAGLD(buf, tt, half) \
  (*reinterpret_cast<const bf16x8*>((buf) + (size_t)(tt) * 1024 + (half) * 512 + lb))

  // 2-deep pipeline: tiles t (cur) / t+1 (nxt) in flight while computing.
  bf16x8 c0 = FRAGLD(ehB, 0, 0), c1 = FRAGLD(ehB, 0, 1),
         c2 = FRAGLD(elB, 0, 0), c3 = FRAGLD(elB, 0, 1);
  bf16x8 n0 = FRAGLD(ehB, 1, 0), n1 = FRAGLD(ehB, 1, 1),
         n2 = FRAGLD(elB, 1, 0), n3 = FRAGLD(elB, 1, 1);

  const f32x4 kz = {0.f, 0.f, 0.f, 0.f};
  #pragma unroll 4
  for (int t = 0; t < 64; ++t) {
    const int tf = (t + 2 < 64) ? t + 2 : 63;   // clamp (dup loads harmless)
    bf16x8 f0 = FRAGLD(ehB, tf, 0), f1 = FRAGLD(ehB, tf, 1),
           f2 = FRAGLD(elB, tf, 0), f3 = FRAGLD(elB, tf, 1);

    f32x4 a0, a1;   // interleave the two row-tiles: dep distance 2 on MFMA pipe
    a0 = mfma16(xh[0][0], c0, kz);  a1 = mfma16(xh[1][0], c0, kz);
    a0 = mfma16(xh[0][1], c1, a0);  a1 = mfma16(xh[1][1], c1, a1);
    a0 = mfma16(xh[0][0], c2, a0);  a1 = mfma16(xh[1][0], c2, a1);
    a0 = mfma16(xh[0][1], c3, a0);  a1 = mfma16(xh[1][1], c3, a1);
    a0 = mfma16(xl[0][0], c0, a0);  a1 = mfma16(xl[1][0], c0, a1);
    a0 = mfma16(xl[0][1], c1, a0);  a1 = mfma16(xl[1][1], c1, a1);

    const float sev = sel[t * 16 + (l & 15)];
    #pragma unroll
    for (int r = 0; r < 4; ++r) {
      {
        const float d = __builtin_fmaf(-2.0f, a0[r], sev);  // d' = se - 2*dot
        const bool c = d < m1v[0][r];
        m2v[0][r] = fminf(m2v[0][r], fmaxf(m1v[0][r], d));
        m1t[0][r] = c ? t : m1t[0][r];
        m1v[0][r] = fminf(m1v[0][r], d);
      }
      {
        const float d = __builtin_fmaf(-2.0f, a1[r], sev);
        const bool c = d < m1v[1][r];
        m2v[1][r] = fminf(m2v[1][r], fmaxf(m1v[1][r], d));
        m1t[1][r] = c ? t : m1t[1][r];
        m1v[1][r] = fminf(m1v[1][r], d);
      }
    }
    c0 = n0; c1 = n1; c2 = n2; c3 = n3;
    n0 = f0; n1 = f1; n2 = f2; n3 = f3;
  }
#undef FRAGLD

  // 16-lane merge (R6/R7-proven); certificate or sentinel
  const int colbase = l & 15;
  #pragma unroll
  for (int rt = 0; rt < 2; ++rt) {
    #pragma unroll
    for (int r = 0; r < 4; ++r) {
      float m1 = m1v[rt][r], m2 = m2v[rt][r];
      unsigned long long key =
          ((unsigned long long)fflip(__float_as_uint(m1)) << 32)
          | (unsigned)(m1t[rt][r] * 16 + colbase);
      #pragma unroll
      for (int off = 1; off < 16; off <<= 1) {
        const unsigned long long ok = __shfl_xor(key, off, 16);
        const float om1 = __shfl_xor(m1, off, 16);
        const float om2 = __shfl_xor(m2, off, 16);
        m2 = fminf(fminf(m2, om2), fmaxf(m1, om1));
        m1 = fminf(m1, om1);
        key = (ok < key) ? ok : key;
      }
      if (colbase == 0) {
        const int row = wrb + rt * 16 + (l >> 4) * 4 + r;
        bidx[row] = (m2 > m1 + EPSB) ? (int)(key & 0xffffffffull) : -1;
      }
    }
  }
}

// ---------------- compact: gather ambiguous rows, <=1 atomic per wave
__global__ __launch_bounds__(256) void vq_compact(const int* __restrict__ bidx,
                                                  int* __restrict__ list,
                                                  int* __restrict__ cnt) {
  const int gid = blockIdx.x * 256 + (int)threadIdx.x;
  const int l = (int)threadIdx.x & 63;
  const bool amb = bidx[gid] < 0;
  const unsigned long long mask = __ballot(amb);
  int base = 0;
  if (l == 0 && mask) base = atomicAdd(cnt, (int)__popcll(mask));
  base = __shfl(base, 0, 64);
  if (amb) {
    const int off = (int)__popcll(mask & ((1ull << l) - 1ull));
    list[base + off] = gid;
  }
}

// ---------------- exact scan: lane = gathered row, 4 independent code-chains
__global__ __launch_bounds__(256) void vq_exact(const float* __restrict__ x,
                                                const float* __restrict__ emb,
                                                const float* __restrict__ se,
                                                const int* __restrict__ list,
                                                const int* __restrict__ cnt,
                                                unsigned long long* __restrict__ keyBest) {
  #pragma clang fp contract(off)
  const int n = *cnt;
  if (n == 0) return;
  const int nW = (int)gridDim.x * 4;                      // 4096 waves
  const int w  = blockIdx.x * 4 + ((int)threadIdx.x >> 6);
  const int l  = (int)threadIdx.x & 63;
  const int ntasks = ((n + 63) >> 6) * 32;                // rowblk x 32 parts

  for (int task = w; task < ntasks; task += nW) {
    const int rowblk = task >> 5;
    const int part   = task & 31;
    const int j0     = part * 32;
    const int idx    = rowblk * 64 + l;
    const bool act   = idx < n;
    const int row    = act ? list[idx] : list[0];
    const float4* xr4 = reinterpret_cast<const float4*>(x + (size_t)row * DDIM);

    // sx: numpy pairwise 8-accumulator (R1-proven order)
    float rr[8];
    {
      const float4 a = xr4[0], b = xr4[1];
      rr[0] = a.x * a.x; rr[1] = a.y * a.y; rr[2] = a.z * a.z; rr[3] = a.w * a.w;
      rr[4] = b.x * b.x; rr[5] = b.y * b.y; rr[6] = b.z * b.z; rr[7] = b.w * b.w;
    }
    #pragma unroll
    for (int i = 2; i < 16; i += 2) {
      const float4 a = xr4[i], b = xr4[i + 1];
      rr[0] += a.x * a.x; rr[1] += a.y * a.y; rr[2] += a.z * a.z; rr[3] += a.w * a.w;
      rr[4] += b.x * b.x; rr[5] += b.y * b.y; rr[6] += b.z * b.z; rr[7] += b.w * b.w;
    }
    const float sx = ((rr[0] + rr[1]) + (rr[2] + rr[3])) + ((rr[4] + rr[5]) + (rr[6] + rr[7]));

    unsigned long long best = ~0ull;
    #pragma unroll 1
    for (int g = 0; g < 8; ++g) {   // 8 groups of 4 codes; 4 independent chains
      const int j = j0 + g * 4;
      const float* e0 = emb + (size_t)(j + 0) * DDIM;   // wave-uniform -> s_load
      const float* e1 = emb + (size_t)(j + 1) * DDIM;
      const float* e2 = emb + (size_t)(j + 2) * DDIM;
      const float* e3 = emb + (size_t)(j + 3) * DDIM;
      float a0 = 0.f, a1 = 0.f, a2 = 0.f, a3 = 0.f;
      #pragma unroll
      for (int ch = 0; ch < 4; ++ch) {   // stream x in 16-float chunks (R3 shape)
        float xq[16];
        #pragma unroll
        for (int q = 0; q < 4; ++q) {
          const float4 v = xr4[ch * 4 + q];
          xq[q * 4 + 0] = v.x; xq[q * 4 + 1] = v.y;
          xq[q * 4 + 2] = v.z; xq[q * 4 + 3] = v.w;
        }
        #pragma unroll
        for (int d = 0; d < 16; ++d) {   // each chain: sequential d=0..63 (R1)
          const int dd = ch * 16 + d;
          a0 = __builtin_fmaf(xq[d], e0[dd], a0);
          a1 = __builtin_fmaf(xq[d], e1[dd], a1);
          a2 = __builtin_fmaf(xq[d], e2[dd], a2);
          a3 = __builtin_fmaf(xq[d], e3[dd], a3);
        }
      }
      const float T0 = sx + se[j + 0];
      const float T1 = sx + se[j + 1];
      const float T2 = sx + se[j + 2];
      const float T3 = sx + se[j + 3];
      const float di0 = __builtin_fmaf(-2.0f, a0, T0);
      const float di1 = __builtin_fmaf(-2.0f, a1, T1);
      const float di2 = __builtin_fmaf(-2.0f, a2, T2);
      const float di3 = __builtin_fmaf(-2.0f, a3, T3);
      unsigned long long k;
      k = ((unsigned long long)fflip(__float_as_uint(di0)) << 32) | (unsigned)(j + 0);
      best = (k < best) ? k : best;
      k = ((unsigned long long)fflip(__float_as_uint(di1)) << 32) | (unsigned)(j + 1);
      best = (k < best) ? k : best;
      k = ((unsigned long long)fflip(__float_as_uint(di2)) << 32) | (unsigned)(j + 2);
      best = (k < best) ? k : best;
      k = ((unsigned long long)fflip(__float_as_uint(di3)) << 32) | (unsigned)(j + 3);
      best = (k < best) ? k : best;
    }
    if (act) atomicMin(&keyBest[row], best);   // (dist asc, j asc) == first-min
  }
}

// ---------------- finalize: 16 lanes x float4 per row (coalesced e-gather)
__global__ __launch_bounds__(256) void vq_finalize(const float* __restrict__ x,
                                                   const float* __restrict__ emb,
                                                   const int* __restrict__ bidx,
                                                   const unsigned long long* __restrict__ keyBest,
                                                   float* __restrict__ out,
                                                   double* __restrict__ loss_accum) {
  #pragma clang fp contract(off)
  __shared__ float wsum[4];
  const int tid = (int)threadIdx.x;
  const int l   = tid & 63;
  const int wid = tid >> 6;
  const int sub = l >> 4;    // row within the wave's quad
  const int q16 = l & 15;    // float4 slot within the row
  float lacc = 0.f;

  #pragma unroll
  for (int it = 0; it < 4; ++it) {   // block covers 64 rows
    const int row = blockIdx.x * 64 + it * 16 + wid * 4 + sub;
    int bi = bidx[row];
    if (bi < 0) bi = (int)(keyBest[row] & 0xffffffffull);
    const float4 xv = reinterpret_cast<const float4*>(x)[(size_t)row * 16 + q16];
    const float4 ev = reinterpret_cast<const float4*>(emb)[(size_t)bi * 16 + q16];
    const float da = ev.x - xv.x;
    const float db = ev.y - xv.y;
    const float dc = ev.z - xv.z;
    const float dd = ev.w - xv.w;
    float4 o;
    o.x = xv.x + da; o.y = xv.y + db; o.z = xv.z + dc; o.w = xv.w + dd;
    reinterpret_cast<float4*>(out)[(size_t)row * 16 + q16] = o;
    lacc += da * da + db * db + dc * dc + dd * dd;   // order-insensitive
    if (q16 == 0) out[(size_t)NROWS * DDIM + row] = (float)bi;
  }
  #pragma unroll
  for (int off = 32; off > 0; off >>= 1) lacc += __shfl_down(lacc, off, 64);
  if (l == 0) wsum[wid] = lacc;
  __syncthreads();
  if (tid == 0)
    atomicAdd(loss_accum, (double)(wsum[0] + wsum[1] + wsum[2] + wsum[3]));
}

// ---------------- scalars
__global__ void vq_scalars(const double* __restrict__ loss_accum,
                           float* __restrict__ out) {
  if (threadIdx.x == 0 && blockIdx.x == 0) {
    const double mm = *loss_accum / (double)((size_t)NROWS * DDIM);
    const float el = (float)mm;
    float* tail = out + (size_t)NROWS * DDIM + NROWS;
    tail[0] = 0.25f * el;
    tail[1] = el;
    tail[2] = 0.0f;
  }
}

// ============================================================================
extern "C" void kernel_launch(void* const* d_in, const int* in_sizes, int n_in,
                              void* d_out, int out_size, void* d_ws, size_t ws_size,
                              hipStream_t stream) {
  const float* x   = (const float*)d_in[0];  // [N, 64]
  const float* emb = (const float*)d_in[1];  // [K, 64]
  float* out = (float*)d_out;
  char* ws = (char*)d_ws;

  double* loss_accum = (double*)(ws + WS_LOSS);
  int*    cnt        = (int*)(ws + WS_CNT);
  float*  se         = (float*)(ws + WS_SE);
  short*  ehB        = (short*)(ws + WS_EHB);
  short*  elB        = (short*)(ws + WS_ELB);
  int*    bidx       = (int*)(ws + WS_BIDX);
  int*    list       = (int*)(ws + WS_LIST);
  unsigned long long* keyBest = (unsigned long long*)(ws + WS_KEY);

  vq_prep<<<NROWS / 256, 256, 0, stream>>>(emb, se, ehB, elB, keyBest,
                                           loss_accum, cnt);
  vq_fused<<<NROWS / 128, 256, 0, stream>>>(x, ehB, elB, se, bidx);
  vq_compact<<<NROWS / 256, 256, 0, stream>>>(bidx, list, cnt);
  vq_exact<<<1024, 256, 0, stream>>>(x, emb, se, list, cnt, keyBest);
  vq_finalize<<<NROWS / 64, 256, 0, stream>>>(x, emb, bidx, keyBest, out,
                                              loss_accum);
  vq_scalars<<<1, 64, 0, stream>>>(loss_accum, out);
}

// Round 9
// 144.087 us; speedup vs baseline: 1.5781x; 1.0483x over previous
//
#include <hip/hip_runtime.h>
#include <hip/hip_bf16.h>
#include <math.h>

// VQ-VAE VectorQuantizer: B=32,T=2048,D=64,K=1024 -> N=65536 rows.
// Round 9: R8 with ONE fix: vq_exact loads the scattered x-row ONCE into
// registers per task (was: re-gathered 8x per task x 32 partitions -> ~8k
// cache-line requests per wave-task, line-pipe-bound at 75us, VALUBusy 7.8%).
// Partitions 32 -> 16 (64 codes/task). Per-code rounding order unchanged:
// sequential d=0..63 fmaf chain, fl(sx+se), fmaf(-2,acc,T), u64 first-min.
// vq_fused / prep / compact / finalize frozen from R8 (absmax 0.0).

typedef __attribute__((ext_vector_type(8))) short bf16x8;
typedef __attribute__((ext_vector_type(4))) float f32x4;

namespace {
constexpr int NROWS  = 65536;
constexpr int DDIM   = 64;
constexpr int KCODES = 1024;
constexpr float EPSB = 8e-5f;   // certificate band; bound ~2.3e-5

// ws layout (bytes) — ~1.8 MB
constexpr size_t WS_LOSS = 0;                            // double
constexpr size_t WS_CNT  = 64;                           // int
constexpr size_t WS_SE   = 256;                          // float[1024]
constexpr size_t WS_EHB  = 8192;                         // bf16 frags 128 KB
constexpr size_t WS_ELB  = WS_EHB + (size_t)65536 * 2;   // 128 KB
constexpr size_t WS_BIDX = WS_ELB + (size_t)65536 * 2;   // int[N]
constexpr size_t WS_LIST = WS_BIDX + (size_t)NROWS * 4;  // int[N]
constexpr size_t WS_KEY  = WS_LIST + (size_t)NROWS * 4;  // u64[N]
}

__device__ inline short f2bf(float v) {
  __hip_bfloat16 h = __float2bfloat16(v);
  return *reinterpret_cast<short*>(&h);
}
__device__ inline float bf2f(short s) {
  __hip_bfloat16 h;
  *reinterpret_cast<short*>(&h) = s;
  return __bfloat162float(h);
}
__device__ inline f32x4 mfma16(bf16x8 a, bf16x8 b, f32x4 c) {
  return __builtin_amdgcn_mfma_f32_16x16x32_bf16(a, b, c, 0, 0, 0);
}
__device__ inline unsigned int fflip(unsigned int b) {
  return b ^ ((unsigned int)((int)b >> 31) | 0x80000000u);
}

// ---------------- prep: init keyBest/loss/cnt, se (numpy pairwise), frag pack
__global__ __launch_bounds__(256) void vq_prep(const float* __restrict__ emb,
                                               float* __restrict__ se,
                                               short* __restrict__ ehB,
                                               short* __restrict__ elB,
                                               unsigned long long* __restrict__ keyBest,
                                               double* __restrict__ loss_accum,
                                               int* __restrict__ cnt) {
  #pragma clang fp contract(off)
  const int gid = blockIdx.x * 256 + (int)threadIdx.x;   // grid = 65536
  if (gid == 0) { *loss_accum = 0.0; *cnt = 0; }
  keyBest[gid] = ~0ull;

  if (gid < KCODES) {   // se[j]: proven pairwise pattern
    const float* e = emb + (size_t)gid * DDIM;
    float r[8];
    #pragma unroll
    for (int j = 0; j < 8; ++j) r[j] = e[j] * e[j];
    #pragma unroll
    for (int i = 8; i < DDIM; i += 8) {
      #pragma unroll
      for (int j = 0; j < 8; ++j) r[j] += e[i + j] * e[i + j];
    }
    se[gid] = ((r[0] + r[1]) + (r[2] + r[3])) + ((r[4] + r[5]) + (r[6] + r[7]));
  }

  // pack frag (t,dc): lane l holds e[t*16+(l&15)][dc*32+(l>>4)*8 + i]  (R5-R8)
  if (gid < 8192) {
    const int t  = gid >> 7;
    const int dc = (gid >> 6) & 1;
    const int l  = gid & 63;
    const int code = t * 16 + (l & 15);
    const int d0   = dc * 32 + (l >> 4) * 8;
    const float* ep = emb + (size_t)code * DDIM + d0;
    const size_t ob = ((size_t)(t * 2 + dc) * 64 + l) * 8;
    #pragma unroll
    for (int i = 0; i < 8; ++i) {
      const float v = ep[i];
      const short h = f2bf(v);
      ehB[ob + i] = h;
      elB[ob + i] = f2bf(v - bf2f(h));
    }
  }
}

// ---------------- fused sweep: wave = 32 rows x 1024 codes, 2-deep prefetch
__global__ __launch_bounds__(256, 2) void vq_fused(const float* __restrict__ x,
                                                   const short* __restrict__ ehB,
                                                   const short* __restrict__ elB,
                                                   const float* __restrict__ se,
                                                   int* __restrict__ bidx) {
  #pragma clang fp contract(off)
  __shared__ float sel[KCODES];
  const int tid = (int)threadIdx.x;
  const int l   = tid & 63;
  const int wid = tid >> 6;
  #pragma unroll
  for (int i = 0; i < 4; ++i) sel[i * 256 + tid] = se[i * 256 + tid];
  __syncthreads();

  // A-fragments for 2 row-tiles (32 rows/wave)
  const int wrb = blockIdx.x * 128 + wid * 32;
  bf16x8 xh[2][2], xl[2][2];
  #pragma unroll
  for (int rt = 0; rt < 2; ++rt) {
    const float* xp = x + (size_t)(wrb + rt * 16 + (l & 15)) * DDIM + (l >> 4) * 8;
    #pragma unroll
    for (int dc = 0; dc < 2; ++dc) {
      const float4 v0 = *reinterpret_cast<const float4*>(xp + dc * 32);
      const float4 v1 = *reinterpret_cast<const float4*>(xp + dc * 32 + 4);
      const float vv[8] = {v0.x, v0.y, v0.z, v0.w, v1.x, v1.y, v1.z, v1.w};
      #pragma unroll
      for (int i = 0; i < 8; ++i) {
        const short h = f2bf(vv[i]);
        xh[rt][dc][i] = h;
        xl[rt][dc][i] = f2bf(vv[i] - bf2f(h));
      }
    }
  }

  float m1v[2][4], m2v[2][4];
  int   m1t[2][4];
  #pragma unroll
  for (int rt = 0; rt < 2; ++rt)
    #pragma unroll
    for (int r = 0; r < 4; ++r) { m1v[rt][r] = INFINITY; m2v[rt][r] = INFINITY; m1t[rt][r] = 0; }

  const size_t lb = (size_t)l * 8;
#define FRAGLD(buf, tt, half) \
  (*reinterpret_cast<const bf16x8*>((buf) + (size_t)(tt) * 1024 + (half) * 512 + lb))

  // 2-deep pipeline: tiles t (cur) / t+1 (nxt) in flight while computing.
  bf16x8 c0 = FRAGLD(ehB, 0, 0), c1 = FRAGLD(ehB, 0, 1),
         c2 = FRAGLD(elB, 0, 0), c3 = FRAGLD(elB, 0, 1);
  bf16x8 n0 = FRAGLD(ehB, 1, 0), n1 = FRAGLD(ehB, 1, 1),
         n2 = FRAGLD(elB, 1, 0), n3 = FRAGLD(elB, 1, 1);

  const f32x4 kz = {0.f, 0.f, 0.f, 0.f};
  #pragma unroll 4
  for (int t = 0; t < 64; ++t) {
    const int tf = (t + 2 < 64) ? t + 2 : 63;   // clamp (dup loads harmless)
    bf16x8 f0 = FRAGLD(ehB, tf, 0), f1 = FRAGLD(ehB, tf, 1),
           f2 = FRAGLD(elB, tf, 0), f3 = FRAGLD(elB, tf, 1);

    f32x4 a0, a1;   // interleave the two row-tiles: dep distance 2 on MFMA pipe
    a0 = mfma16(xh[0][0], c0, kz);  a1 = mfma16(xh[1][0], c0, kz);
    a0 = mfma16(xh[0][1], c1, a0);  a1 = mfma16(xh[1][1], c1, a1);
    a0 = mfma16(xh[0][0], c2, a0);  a1 = mfma16(xh[1][0], c2, a1);
    a0 = mfma16(xh[0][1], c3, a0);  a1 = mfma16(xh[1][1], c3, a1);
    a0 = mfma16(xl[0][0], c0, a0);  a1 = mfma16(xl[1][0], c0, a1);
    a0 = mfma16(xl[0][1], c1, a0);  a1 = mfma16(xl[1][1], c1, a1);

    const float sev = sel[t * 16 + (l & 15)];
    #pragma unroll
    for (int r = 0; r < 4; ++r) {
      {
        const float d = __builtin_fmaf(-2.0f, a0[r], sev);  // d' = se - 2*dot
        const bool c = d < m1v[0][r];
        m2v[0][r] = fminf(m2v[0][r], fmaxf(m1v[0][r], d));
        m1t[0][r] = c ? t : m1t[0][r];
        m1v[0][r] = fminf(m1v[0][r], d);
      }
      {
        const float d = __builtin_fmaf(-2.0f, a1[r], sev);
        const bool c = d < m1v[1][r];
        m2v[1][r] = fminf(m2v[1][r], fmaxf(m1v[1][r], d));
        m1t[1][r] = c ? t : m1t[1][r];
        m1v[1][r] = fminf(m1v[1][r], d);
      }
    }
    c0 = n0; c1 = n1; c2 = n2; c3 = n3;
    n0 = f0; n1 = f1; n2 = f2; n3 = f3;
  }
#undef FRAGLD

  // 16-lane merge (R6-R8-proven); certificate or sentinel
  const int colbase = l & 15;
  #pragma unroll
  for (int rt = 0; rt < 2; ++rt) {
    #pragma unroll
    for (int r = 0; r < 4; ++r) {
      float m1 = m1v[rt][r], m2 = m2v[rt][r];
      unsigned long long key =
          ((unsigned long long)fflip(__float_as_uint(m1)) << 32)
          | (unsigned)(m1t[rt][r] * 16 + colbase);
      #pragma unroll
      for (int off = 1; off < 16; off <<= 1) {
        const unsigned long long ok = __shfl_xor(key, off, 16);
        const float om1 = __shfl_xor(m1, off, 16);
        const float om2 = __shfl_xor(m2, off, 16);
        m2 = fminf(fminf(m2, om2), fmaxf(m1, om1));
        m1 = fminf(m1, om1);
        key = (ok < key) ? ok : key;
      }
      if (colbase == 0) {
        const int row = wrb + rt * 16 + (l >> 4) * 4 + r;
        bidx[row] = (m2 > m1 + EPSB) ? (int)(key & 0xffffffffull) : -1;
      }
    }
  }
}

// ---------------- compact: gather ambiguous rows, <=1 atomic per wave
__global__ __launch_bounds__(256) void vq_compact(const int* __restrict__ bidx,
                                                  int* __restrict__ list,
                                                  int* __restrict__ cnt) {
  const int gid = blockIdx.x * 256 + (int)threadIdx.x;
  const int l = (int)threadIdx.x & 63;
  const bool amb = bidx[gid] < 0;
  const unsigned long long mask = __ballot(amb);
  int base = 0;
  if (l == 0 && mask) base = atomicAdd(cnt, (int)__popcll(mask));
  base = __shfl(base, 0, 64);
  if (amb) {
    const int off = (int)__popcll(mask & ((1ull << l) - 1ull));
    list[base + off] = gid;
  }
}

// ---------------- exact scan: lane = gathered row; x loaded ONCE to regs;
// 16 code-partitions x 64 codes; 4 independent bit-exact chains per group.
__global__ __launch_bounds__(256) void vq_exact(const float* __restrict__ x,
                                                const float* __restrict__ emb,
                                                const float* __restrict__ se,
                                                const int* __restrict__ list,
                                                const int* __restrict__ cnt,
                                                unsigned long long* __restrict__ keyBest) {
  #pragma clang fp contract(off)
  const int n = *cnt;
  if (n == 0) return;
  const int nW = (int)gridDim.x * 4;                      // 4096 waves
  const int w  = blockIdx.x * 4 + ((int)threadIdx.x >> 6);
  const int l  = (int)threadIdx.x & 63;
  const int ntasks = ((n + 63) >> 6) * 16;                // rowblk x 16 parts

  for (int task = w; task < ntasks; task += nW) {
    const int rowblk = task >> 4;
    const int part   = task & 15;
    const int j0     = part * 64;
    const int idx    = rowblk * 64 + l;
    const bool act   = idx < n;
    const int row    = act ? list[idx] : list[0];
    const float4* xr4 = reinterpret_cast<const float4*>(x + (size_t)row * DDIM);

    // x row -> registers ONCE (16 scattered float4 gathers, the minimum)
    float xv[DDIM];
    #pragma unroll
    for (int q = 0; q < 16; ++q) {
      const float4 v = xr4[q];
      xv[q * 4 + 0] = v.x; xv[q * 4 + 1] = v.y;
      xv[q * 4 + 2] = v.z; xv[q * 4 + 3] = v.w;
    }

    // sx: numpy pairwise 8-accumulator (R1-proven order)
    float rr[8];
    #pragma unroll
    for (int j = 0; j < 8; ++j) rr[j] = xv[j] * xv[j];
    #pragma unroll
    for (int i = 8; i < DDIM; i += 8) {
      #pragma unroll
      for (int j = 0; j < 8; ++j) rr[j] += xv[i + j] * xv[i + j];
    }
    const float sx = ((rr[0] + rr[1]) + (rr[2] + rr[3])) + ((rr[4] + rr[5]) + (rr[6] + rr[7]));

    unsigned long long best = ~0ull;
    #pragma unroll 1
    for (int g = 0; g < 16; ++g) {   // 16 groups of 4 codes; 4 independent chains
      const int j = j0 + g * 4;
      const float* e0 = emb + (size_t)(j + 0) * DDIM;   // wave-uniform
      const float* e1 = emb + (size_t)(j + 1) * DDIM;
      const float* e2 = emb + (size_t)(j + 2) * DDIM;
      const float* e3 = emb + (size_t)(j + 3) * DDIM;
      float a0 = 0.f, a1 = 0.f, a2 = 0.f, a3 = 0.f;
      #pragma unroll
      for (int d = 0; d < DDIM; ++d) {   // each chain: sequential d=0..63 (R1)
        a0 = __builtin_fmaf(xv[d], e0[d], a0);
        a1 = __builtin_fmaf(xv[d], e1[d], a1);
        a2 = __builtin_fmaf(xv[d], e2[d], a2);
        a3 = __builtin_fmaf(xv[d], e3[d], a3);
      }
      const float T0 = sx + se[j + 0];
      const float T1 = sx + se[j + 1];
      const float T2 = sx + se[j + 2];
      const float T3 = sx + se[j + 3];
      const float di0 = __builtin_fmaf(-2.0f, a0, T0);
      const float di1 = __builtin_fmaf(-2.0f, a1, T1);
      const float di2 = __builtin_fmaf(-2.0f, a2, T2);
      const float di3 = __builtin_fmaf(-2.0f, a3, T3);
      unsigned long long k;
      k = ((unsigned long long)fflip(__float_as_uint(di0)) << 32) | (unsigned)(j + 0);
      best = (k < best) ? k : best;
      k = ((unsigned long long)fflip(__float_as_uint(di1)) << 32) | (unsigned)(j + 1);
      best = (k < best) ? k : best;
      k = ((unsigned long long)fflip(__float_as_uint(di2)) << 32) | (unsigned)(j + 2);
      best = (k < best) ? k : best;
      k = ((unsigned long long)fflip(__float_as_uint(di3)) << 32) | (unsigned)(j + 3);
      best = (k < best) ? k : best;
    }
    if (act) atomicMin(&keyBest[row], best);   // (dist asc, j asc) == first-min
  }
}

// ---------------- finalize: 16 lanes x float4 per row (coalesced e-gather)
__global__ __launch_bounds__(256) void vq_finalize(const float* __restrict__ x,
                                                   const float* __restrict__ emb,
                                                   const int* __restrict__ bidx,
                                                   const unsigned long long* __restrict__ keyBest,
                                                   float* __restrict__ out,
                                                   double* __restrict__ loss_accum) {
  #pragma clang fp contract(off)
  __shared__ float wsum[4];
  const int tid = (int)threadIdx.x;
  const int l   = tid & 63;
  const int wid = tid >> 6;
  const int sub = l >> 4;    // row within the wave's quad
  const int q16 = l & 15;    // float4 slot within the row
  float lacc = 0.f;

  #pragma unroll
  for (int it = 0; it < 4; ++it) {   // block covers 64 rows
    const int row = blockIdx.x * 64 + it * 16 + wid * 4 + sub;
    int bi = bidx[row];
    if (bi < 0) bi = (int)(keyBest[row] & 0xffffffffull);
    const float4 xv = reinterpret_cast<const float4*>(x)[(size_t)row * 16 + q16];
    const float4 ev = reinterpret_cast<const float4*>(emb)[(size_t)bi * 16 + q16];
    const float da = ev.x - xv.x;
    const float db = ev.y - xv.y;
    const float dc = ev.z - xv.z;
    const float dd = ev.w - xv.w;
    float4 o;
    o.x = xv.x + da; o.y = xv.y + db; o.z = xv.z + dc; o.w = xv.w + dd;
    reinterpret_cast<float4*>(out)[(size_t)row * 16 + q16] = o;
    lacc += da * da + db * db + dc * dc + dd * dd;   // order-insensitive
    if (q16 == 0) out[(size_t)NROWS * DDIM + row] = (float)bi;
  }
  #pragma unroll
  for (int off = 32; off > 0; off >>= 1) lacc += __shfl_down(lacc, off, 64);
  if (l == 0) wsum[wid] = lacc;
  __syncthreads();
  if (tid == 0)
    atomicAdd(loss_accum, (double)(wsum[0] + wsum[1] + wsum[2] + wsum[3]));
}

// ---------------- scalars
__global__ void vq_scalars(const double* __restrict__ loss_accum,
                           float* __restrict__ out) {
  if (threadIdx.x == 0 && blockIdx.x == 0) {
    const double mm = *loss_accum / (double)((size_t)NROWS * DDIM);
    const float el = (float)mm;
    float* tail = out + (size_t)NROWS * DDIM + NROWS;
    tail[0] = 0.25f * el;
    tail[1] = el;
    tail[2] = 0.0f;
  }
}

// ============================================================================
extern "C" void kernel_launch(void* const* d_in, const int* in_sizes, int n_in,
                              void* d_out, int out_size, void* d_ws, size_t ws_size,
                              hipStream_t stream) {
  const float* x   = (const float*)d_in[0];  // [N, 64]
  const float* emb = (const float*)d_in[1];  // [K, 64]
  float* out = (float*)d_out;
  char* ws = (char*)d_ws;

  double* loss_accum = (double*)(ws + WS_LOSS);
  int*    cnt        = (int*)(ws + WS_CNT);
  float*  se         = (float*)(ws + WS_SE);
  short*  ehB        = (short*)(ws + WS_EHB);
  short*  elB        = (short*)(ws + WS_ELB);
  int*    bidx       = (int*)(ws + WS_BIDX);
  int*    list       = (int*)(ws + WS_LIST);
  unsigned long long* keyBest = (unsigned long long*)(ws + WS_KEY);

  vq_prep<<<NROWS / 256, 256, 0, stream>>>(emb, se, ehB, elB, keyBest,
                                           loss_accum, cnt);
  vq_fused<<<NROWS / 128, 256, 0, stream>>>(x, ehB, elB, se, bidx);
  vq_compact<<<NROWS / 256, 256, 0, stream>>>(bidx, list, cnt);
  vq_exact<<<1024, 256, 0, stream>>>(x, emb, se, list, cnt, keyBest);
  vq_finalize<<<NROWS / 64, 256, 0, stream>>>(x, emb, bidx, keyBest, out,
                                              loss_accum);
  vq_scalars<<<1, 64, 0, stream>>>(loss_accum, out);
}